// Round 1
// baseline (811.048 us; speedup 1.0000x reference)
//
#include <hip/hip_runtime.h>

// SearchTransfer: patch cosine-similarity argmax + multi-level gather/fold.
// Decomposition: patch-dot = 9-tap diagonal-shift sum of pixel Gram matrix S
// (K=256 GEMM instead of K=2304). transfer(v) == gather (rel_val cancels).
//
// ws layout (floats):
//   [0      .. 9216 )  ps_i : per-pixel sum of squares, img
//   [9216   .. 18432)  ps_r : per-pixel sum of squares, ref
//   [18432  .. 27648)  kn   : key patch norms  (ref)
//   [27648  .. 36864)  qn   : query patch norms (img)
//   [36864  .. 46080)  ridx : argmax index per query (int32)
//   [46080  .. +2304*2304) S : per-batch pixel Gram matrix S[q][p]

__global__ __launch_bounds__(256) void k_pixsq(const float* __restrict__ img,
                                               const float* __restrict__ ref,
                                               float* __restrict__ psi,
                                               float* __restrict__ psr) {
  int pix = blockIdx.x * 256 + threadIdx.x;   // [0, 4*2304)
  int b = pix / 2304, p = pix - b * 2304;
  const float* ib = img + (size_t)b * 256 * 2304 + p;
  const float* rb = ref + (size_t)b * 256 * 2304 + p;
  float si = 0.f, sr = 0.f;
#pragma unroll 8
  for (int c = 0; c < 256; ++c) {
    float x = ib[c * 2304]; si = fmaf(x, x, si);
    float y = rb[c * 2304]; sr = fmaf(y, y, sr);
  }
  psi[pix] = si; psr[pix] = sr;
}

__global__ __launch_bounds__(256) void k_norm(const float* __restrict__ psr,
                                              const float* __restrict__ psi,
                                              float* __restrict__ kn,
                                              float* __restrict__ qn) {
  int pix = blockIdx.x * 256 + threadIdx.x;
  int b = pix / 2304, p = pix - b * 2304;
  int py = p / 48, px = p - py * 48;
  float sr = 0.f, si = 0.f;
#pragma unroll
  for (int dy = -1; dy <= 1; ++dy) {
#pragma unroll
    for (int dx = -1; dx <= 1; ++dx) {
      if (py + dy < 0 || py + dy >= 48 || px + dx < 0 || px + dx >= 48) continue;
      int n = pix + dy * 48 + dx;
      sr += psr[n]; si += psi[n];
    }
  }
  kn[pix] = fmaxf(sqrtf(sr), 1e-12f);
  qn[pix] = fmaxf(sqrtf(si), 1e-12f);
}

// S[q][p] = sum_c A[c*2304+q] * Bm[c*2304+p]   (A=img plane, Bm=ref plane)
// 128x128 tile, 256 threads, 8x8 acc/thread, K-step 8.
__global__ __launch_bounds__(256) void k_gemm(const float* __restrict__ A,
                                              const float* __restrict__ Bm,
                                              float* __restrict__ S) {
  __shared__ float As[8][128];
  __shared__ float Bs[8][128];
  const int t = threadIdx.x;
  const int q0 = blockIdx.y * 128, p0 = blockIdx.x * 128;
  const int lr = t >> 5, lc = (t & 31) << 2;   // staging: row c, col
  const int tq = t >> 4, tp = t & 15;          // compute: 16x16 thread grid
  float acc[8][8];
#pragma unroll
  for (int u = 0; u < 8; ++u)
#pragma unroll
    for (int v = 0; v < 8; ++v) acc[u][v] = 0.f;

  for (int c0 = 0; c0 < 256; c0 += 8) {
    float4 a4 = *(const float4*)(A  + (c0 + lr) * 2304 + q0 + lc);
    float4 b4 = *(const float4*)(Bm + (c0 + lr) * 2304 + p0 + lc);
    __syncthreads();
    *(float4*)(&As[lr][lc]) = a4;
    *(float4*)(&Bs[lr][lc]) = b4;
    __syncthreads();
#pragma unroll
    for (int kk = 0; kk < 8; ++kk) {
      float4 a0 = *(const float4*)(&As[kk][tq * 8]);
      float4 a1 = *(const float4*)(&As[kk][tq * 8 + 4]);
      float4 b0 = *(const float4*)(&Bs[kk][tp * 4]);        // cols tp*4..+3
      float4 b1 = *(const float4*)(&Bs[kk][64 + tp * 4]);   // cols 64+tp*4..+3
      float av[8] = {a0.x, a0.y, a0.z, a0.w, a1.x, a1.y, a1.z, a1.w};
      float bv[8] = {b0.x, b0.y, b0.z, b0.w, b1.x, b1.y, b1.z, b1.w};
#pragma unroll
      for (int u = 0; u < 8; ++u)
#pragma unroll
        for (int v = 0; v < 8; ++v)
          acc[u][v] = fmaf(av[u], bv[v], acc[u][v]);
    }
  }
#pragma unroll
  for (int u = 0; u < 8; ++u) {
    int q = q0 + tq * 8 + u;
    float* o = S + (size_t)q * 2304 + p0;
    *(float4*)(o + tp * 4)      = make_float4(acc[u][0], acc[u][1], acc[u][2], acc[u][3]);
    *(float4*)(o + 64 + tp * 4) = make_float4(acc[u][4], acc[u][5], acc[u][6], acc[u][7]);
  }
}

// Per query q: rel_raw(p) = sum_{dy,dx} S[q+48dy+dx][p+48dy+dx] (masked),
// argmax_p of rel_raw/kn[p]; S_out = max / qn[q].
__global__ __launch_bounds__(256) void k_argmax(const float* __restrict__ S,
                                                const float* __restrict__ kn,
                                                const float* __restrict__ qn,
                                                int* __restrict__ oidx,
                                                float* __restrict__ oval) {
  const int q = blockIdx.x;
  const int qy = q / 48, qx = q - qy * 48;
  const int t = threadIdx.x;
  float best = -1e30f; int bidx = 0;
  for (int k = 0; k < 9; ++k) {
    int p = (k << 8) + t;                      // 9*256 = 2304
    int py = p / 48, px = p - py * 48;
    float s = 0.f;
#pragma unroll
    for (int dy = -1; dy <= 1; ++dy) {
      if (qy + dy < 0 || qy + dy >= 48) continue;
#pragma unroll
      for (int dx = -1; dx <= 1; ++dx) {
        if (qx + dx < 0 || qx + dx >= 48) continue;
        if (py + dy >= 0 && py + dy < 48 && px + dx >= 0 && px + dx < 48)
          s += S[(size_t)(q + dy * 48 + dx) * 2304 + (p + dy * 48 + dx)];
      }
    }
    float v = s / kn[p];
    if (v > best || (v == best && p < bidx)) { best = v; bidx = p; }
  }
  // wave (64) shuffle reduce, first-index tie-break
  int lane = t & 63, wid = t >> 6;
#pragma unroll
  for (int off = 32; off; off >>= 1) {
    float ov = __shfl_down(best, off);
    int   oi = __shfl_down(bidx, off);
    if (ov > best || (ov == best && oi < bidx)) { best = ov; bidx = oi; }
  }
  __shared__ float sv[4];
  __shared__ int   si4[4];
  if (lane == 0) { sv[wid] = best; si4[wid] = bidx; }
  __syncthreads();
  if (t == 0) {
#pragma unroll
    for (int i = 1; i < 4; ++i)
      if (sv[i] > best || (sv[i] == best && si4[i] < bidx)) { best = sv[i]; bidx = si4[i]; }
    oidx[q] = bidx;
    oval[q] = best / qn[q];
  }
}

// Fold with count-normalization. For stride sc (k=3sc, pad=sc), each output
// pixel gets <=3x3 contributions: oy = h/sc + 1 - ii, src y = sc*(my-1+ii)+h%sc.
__global__ __launch_bounds__(256) void k_fold(const float* __restrict__ cl,
                                              const int* __restrict__ ridx,
                                              float* __restrict__ out,
                                              int Cc, int sc, int Hh) {
  int tid = blockIdx.x * 256 + threadIdx.x;
  int w = tid % Hh;
  int r1 = tid / Hh;
  int h = r1 % Hh;
  int r2 = r1 / Hh;
  int c = r2 % Cc;
  int b = r2 / Cc;
  int hi = h / sc, hr = h - hi * sc;
  int wi = w / sc, wr = w - wi * sc;
  float sum = 0.f; int cnt = 0;
  for (int ii = 0; ii < 3; ++ii) {
    int oy = hi + 1 - ii;
    if (oy < 0 || oy >= 48) continue;
    for (int jj = 0; jj < 3; ++jj) {
      int ox = wi + 1 - jj;
      if (ox < 0 || ox >= 48) continue;
      ++cnt;
      int m = ridx[b * 2304 + oy * 48 + ox];
      int my = m / 48, mx = m - my * 48;
      int y = sc * (my - 1 + ii) + hr;
      int x = sc * (mx - 1 + jj) + wr;
      if (y >= 0 && y < Hh && x >= 0 && x < Hh)
        sum += cl[(((size_t)b * Cc + c) * Hh + y) * Hh + x];
    }
  }
  out[tid] = sum / (float)cnt;
}

extern "C" void kernel_launch(void* const* d_in, const int* in_sizes, int n_in,
                              void* d_out, int out_size, void* d_ws, size_t ws_size,
                              hipStream_t stream) {
  const float* img = (const float*)d_in[0];   // dh_img_lv3 [4,256,48,48]
  const float* ref = (const float*)d_in[1];   // dh_ref_lv3 [4,256,48,48]
  const float* cl1 = (const float*)d_in[2];   // [4,64,192,192]
  const float* cl2 = (const float*)d_in[3];   // [4,128,96,96]
  const float* cl3 = (const float*)d_in[4];   // [4,256,48,48]
  float* out = (float*)d_out;

  float* ws   = (float*)d_ws;
  float* ps_i = ws;
  float* ps_r = ws + 9216;
  float* kn   = ws + 18432;
  float* qn   = ws + 27648;
  int*   ridx = (int*)(ws + 36864);
  float* S    = ws + 46080;                   // 2304*2304 floats, per-batch reuse

  k_pixsq<<<36, 256, 0, stream>>>(img, ref, ps_i, ps_r);
  k_norm<<<36, 256, 0, stream>>>(ps_r, ps_i, kn, qn);

  for (int b = 0; b < 4; ++b) {
    k_gemm<<<dim3(18, 18), 256, 0, stream>>>(img + b * 589824, ref + b * 589824, S);
    k_argmax<<<2304, 256, 0, stream>>>(S, kn + b * 2304, qn + b * 2304,
                                       ridx + b * 2304, out + b * 2304);
  }

  // outputs: S @0 (9216), T3 @9216 (2359296), T2 @2368512 (4718592), T1 @7087104 (9437184)
  k_fold<<<9216, 256, 0, stream>>>(cl3, ridx, out + 9216,    256, 1, 48);
  k_fold<<<18432, 256, 0, stream>>>(cl2, ridx, out + 2368512, 128, 2, 96);
  k_fold<<<36864, 256, 0, stream>>>(cl1, ridx, out + 7087104, 64, 4, 192);
}

// Round 2
// 807.316 us; speedup vs baseline: 1.0046x; 1.0046x over previous
//
#include <hip/hip_runtime.h>

// SearchTransfer: patch cosine-similarity argmax + multi-level gather/fold.
// rel = 9-tap diagonal-shift sum of pixel Gram S (K=256); transfer == gather.
//
// ws floats: ps_i[9216] ps_r[9216] ikn[9216] iqn[9216] ridx[9216(int)]
//            big region @46080: S (per-batch or x4) / fold scratch t (reused)

#define HW3 2304
#define PLANE 589824      // 256*2304
#define SSTRIDE 5308416LL // 2304*2304

// ---- per-pixel sum of squares: 576 blocks, 16 pixels x 16 channel-groups ----
__global__ __launch_bounds__(256) void k_pixsq(const float* __restrict__ img,
                                               const float* __restrict__ ref,
                                               float* __restrict__ psi,
                                               float* __restrict__ psr) {
  __shared__ float ri[16][17], rr[16][17];
  int t = threadIdx.x;
  int pl = t & 15, cg = t >> 4;
  int pix = blockIdx.x * 16 + pl;            // [0, 9216)
  int b = pix / HW3, p = pix - b * HW3;
  const float* ib = img + (size_t)b * PLANE + p;
  const float* rb = ref + (size_t)b * PLANE + p;
  float si = 0.f, sr = 0.f;
#pragma unroll
  for (int c = 0; c < 16; ++c) {
    float x = ib[(cg * 16 + c) * HW3]; si = fmaf(x, x, si);
    float y = rb[(cg * 16 + c) * HW3]; sr = fmaf(y, y, sr);
  }
  ri[pl][cg] = si; rr[pl][cg] = sr;
  __syncthreads();
  if (t < 16) {
    float a = 0.f, s2 = 0.f;
#pragma unroll
    for (int g = 0; g < 16; ++g) { a += ri[t][g]; s2 += rr[t][g]; }
    int pix2 = blockIdx.x * 16 + t;
    psi[pix2] = a; psr[pix2] = s2;
  }
}

// ---- 3x3 box sum of pixel sums -> reciprocal patch norms ----
__global__ __launch_bounds__(256) void k_norm(const float* __restrict__ psr,
                                              const float* __restrict__ psi,
                                              float* __restrict__ ikn,
                                              float* __restrict__ iqn) {
  int pix = blockIdx.x * 256 + threadIdx.x;
  int b = pix / HW3, p = pix - b * HW3;
  int py = p / 48, px = p - py * 48;
  float sr = 0.f, si = 0.f;
#pragma unroll
  for (int dy = -1; dy <= 1; ++dy) {
#pragma unroll
    for (int dx = -1; dx <= 1; ++dx) {
      if (py + dy < 0 || py + dy >= 48 || px + dx < 0 || px + dx >= 48) continue;
      int n = pix + dy * 48 + dx;
      sr += psr[n]; si += psi[n];
    }
  }
  ikn[pix] = 1.0f / fmaxf(sqrtf(sr), 1e-12f);
  iqn[pix] = 1.0f / fmaxf(sqrtf(si), 1e-12f);
}

// ---- S[q][p] = sum_c img[c,q]*ref[c,p], 128x128 tile, batched over z ----
__global__ __launch_bounds__(256) void k_gemm(const float* __restrict__ img,
                                              const float* __restrict__ ref,
                                              float* __restrict__ S,
                                              int b0, long long sstride) {
  __shared__ float As[8][128];
  __shared__ float Bs[8][128];
  const float* A  = img + (size_t)(b0 + blockIdx.z) * PLANE;
  const float* Bm = ref + (size_t)(b0 + blockIdx.z) * PLANE;
  float* Sb = S + (size_t)blockIdx.z * sstride;
  const int t = threadIdx.x;
  const int q0 = blockIdx.y * 128, p0 = blockIdx.x * 128;
  const int lr = t >> 5, lc = (t & 31) << 2;
  const int tq = t >> 4, tp = t & 15;
  float acc[8][8];
#pragma unroll
  for (int u = 0; u < 8; ++u)
#pragma unroll
    for (int v = 0; v < 8; ++v) acc[u][v] = 0.f;

  for (int c0 = 0; c0 < 256; c0 += 8) {
    float4 a4 = *(const float4*)(A  + (c0 + lr) * HW3 + q0 + lc);
    float4 b4 = *(const float4*)(Bm + (c0 + lr) * HW3 + p0 + lc);
    __syncthreads();
    *(float4*)(&As[lr][lc]) = a4;
    *(float4*)(&Bs[lr][lc]) = b4;
    __syncthreads();
#pragma unroll
    for (int kk = 0; kk < 8; ++kk) {
      float4 a0 = *(const float4*)(&As[kk][tq * 8]);
      float4 a1 = *(const float4*)(&As[kk][tq * 8 + 4]);
      float4 b0 = *(const float4*)(&Bs[kk][tp * 4]);
      float4 b1 = *(const float4*)(&Bs[kk][64 + tp * 4]);
      float av[8] = {a0.x, a0.y, a0.z, a0.w, a1.x, a1.y, a1.z, a1.w};
      float bv[8] = {b0.x, b0.y, b0.z, b0.w, b1.x, b1.y, b1.z, b1.w};
#pragma unroll
      for (int u = 0; u < 8; ++u)
#pragma unroll
        for (int v = 0; v < 8; ++v)
          acc[u][v] = fmaf(av[u], bv[v], acc[u][v]);
    }
  }
#pragma unroll
  for (int u = 0; u < 8; ++u) {
    int q = q0 + tq * 8 + u;
    float* o = Sb + (size_t)q * HW3 + p0;
    *(float4*)(o + tp * 4)      = make_float4(acc[u][0], acc[u][1], acc[u][2], acc[u][3]);
    *(float4*)(o + 64 + tp * 4) = make_float4(acc[u][4], acc[u][5], acc[u][6], acc[u][7]);
  }
}

// ---- argmax over keys, 2x2 query tile per block, LDS-staged S rows ----
__global__ __launch_bounds__(256) void k_argmax2(const float* __restrict__ S,
                                                 const float* __restrict__ ikn,
                                                 const float* __restrict__ iqn,
                                                 int* __restrict__ oidx,
                                                 float* __restrict__ oval,
                                                 int b0, long long sstride) {
  __shared__ float L[16][354];
  __shared__ float rv[4][4];
  __shared__ int   ri4[4][4];
  const int b = b0 + blockIdx.z;
  const float* Sb = S + (size_t)blockIdx.z * sstride;
  const float* iknb = ikn + b * HW3;
  const float* iqnb = iqn + b * HW3;
  const int qy0 = blockIdx.y * 2, qx0 = blockIdx.x * 2;
  const int t = threadIdx.x;

  float best[4]; int bid[4];
#pragma unroll
  for (int i = 0; i < 4; ++i) { best[i] = -1e30f; bid[i] = 0; }

  for (int pc = 0; pc < 9; ++pc) {
    const int cbase = pc * 256 - 49;
    for (int e = t; e < 16 * 354; e += 256) {
      int row = e / 354, col = e - row * 354;
      int u = row >> 2, v = row & 3;
      int ry = qy0 - 1 + u, rx = qx0 - 1 + v;
      int c = cbase + col;
      float val = 0.f;
      if (ry >= 0 && ry < 48 && rx >= 0 && rx < 48 && c >= 0 && c < HW3)
        val = Sb[(size_t)(ry * 48 + rx) * HW3 + c];
      L[row][col] = val;
    }
    __syncthreads();
    const int p = pc * 256 + t;
    const int py = p / 48, px = p - py * 48;
#pragma unroll
    for (int a = 0; a < 2; ++a)
#pragma unroll
      for (int bb = 0; bb < 2; ++bb) {
        const int qy = qy0 + a, qx = qx0 + bb;
        float s = 0.f;
#pragma unroll
        for (int dy = -1; dy <= 1; ++dy) {
          if (qy + dy < 0 || qy + dy >= 48 || py + dy < 0 || py + dy >= 48) continue;
#pragma unroll
          for (int dx = -1; dx <= 1; ++dx) {
            if (qx + dx < 0 || qx + dx >= 48 || px + dx < 0 || px + dx >= 48) continue;
            s += L[(a + dy + 1) * 4 + (bb + dx + 1)][t + 49 + dy * 48 + dx];
          }
        }
        float v = s * iknb[p];
        int qi = a * 2 + bb;
        if (v > best[qi]) { best[qi] = v; bid[qi] = p; }
      }
    __syncthreads();
  }

  int lane = t & 63, wv = t >> 6;
#pragma unroll
  for (int qi = 0; qi < 4; ++qi) {
    float bv = best[qi]; int bi = bid[qi];
#pragma unroll
    for (int off = 32; off; off >>= 1) {
      float ov = __shfl_down(bv, off);
      int   oi = __shfl_down(bi, off);
      if (ov > bv || (ov == bv && oi < bi)) { bv = ov; bi = oi; }
    }
    if (lane == 0) { rv[qi][wv] = bv; ri4[qi][wv] = bi; }
  }
  __syncthreads();
  if (t < 4) {
    float bv = rv[t][0]; int bi = ri4[t][0];
#pragma unroll
    for (int w = 1; w < 4; ++w)
      if (rv[t][w] > bv || (rv[t][w] == bv && ri4[t][w] < bi)) { bv = rv[t][w]; bi = ri4[t][w]; }
    int qy = qy0 + (t >> 1), qx = qx0 + (t & 1), q = qy * 48 + qx;
    oidx[b * HW3 + q] = bi;
    oval[b * HW3 + q] = bv * iqnb[q];
  }
}

// ---- tiled transpose cl[b][c][pix] -> t[z][pix][c] ----
__global__ __launch_bounds__(256) void k_tr(const float* __restrict__ src,
                                            float* __restrict__ dst,
                                            int C, int HW, int b0) {
  __shared__ float sm[64][65];
  int pix0 = blockIdx.x * 64, c0 = blockIdx.y * 64;
  const float* s = src + (size_t)(b0 + blockIdx.z) * C * HW;
  float* d = dst + (size_t)blockIdx.z * HW * C;
  int lane = threadIdx.x & 63, q4 = threadIdx.x >> 6;
#pragma unroll
  for (int r = 0; r < 16; ++r) {
    int cl = r * 4 + q4;
    sm[cl][lane] = s[(size_t)(c0 + cl) * HW + pix0 + lane];
  }
  __syncthreads();
#pragma unroll
  for (int r = 0; r < 16; ++r) {
    int pl = r * 4 + q4;
    d[(size_t)(pix0 + pl) * C + c0 + lane] = sm[lane][pl];
  }
}

// ---- gather+fold in channel-last, coalesced, LDS transpose on write ----
__global__ __launch_bounds__(256) void k_foldgather(const float* __restrict__ t,
                                                    const int* __restrict__ ridx,
                                                    float* __restrict__ out,
                                                    int C, int H, int sc, int b0) {
  __shared__ int   soff[64][9];
  __shared__ float sicnt[64];
  __shared__ float tr[64][65];
  const int HW = H * H;
  const int b = b0 + blockIdx.y;
  const float* tb = t + (size_t)blockIdx.y * HW * C;
  const int* rb = ridx + b * HW3;
  const int pix0 = blockIdx.x * 64;

  for (int e = threadIdx.x; e < 576; e += 256) {
    int op = e / 9, tap = e - op * 9;
    int pix = pix0 + op;
    int h = pix / H, w = pix - h * H;
    int hi = h / sc, hr = h - hi * sc;
    int wi = w / sc, wr = w - wi * sc;
    int ii = tap / 3, jj = tap - ii * 3;
    int oy = hi + 1 - ii, ox = wi + 1 - jj;
    int off = -1;
    if (oy >= 0 && oy < 48 && ox >= 0 && ox < 48) {
      int m = rb[oy * 48 + ox];
      int my = m / 48, mx = m - my * 48;
      int y = sc * (my - 1 + ii) + hr;
      int x = sc * (mx - 1 + jj) + wr;
      if (y >= 0 && y < H && x >= 0 && x < H) off = y * H + x;
    }
    soff[op][tap] = off;
    if (tap == 0) {
      int cnt = 0;
#pragma unroll
      for (int i2 = 0; i2 < 3; ++i2)
#pragma unroll
        for (int j2 = 0; j2 < 3; ++j2) {
          int oy2 = hi + 1 - i2, ox2 = wi + 1 - j2;
          if (oy2 >= 0 && oy2 < 48 && ox2 >= 0 && ox2 < 48) ++cnt;
        }
      sicnt[op] = 1.0f / (float)cnt;
    }
  }
  __syncthreads();

  const int g = threadIdx.x >> 6, lane = threadIdx.x & 63;
  for (int c0 = 0; c0 < C; c0 += 64) {
#pragma unroll
    for (int o = 0; o < 16; ++o) {
      int op = g * 16 + o;
      float s = 0.f;
#pragma unroll
      for (int tp = 0; tp < 9; ++tp) {
        int off = soff[op][tp];
        if (off >= 0) s += tb[(size_t)off * C + c0 + lane];
      }
      tr[op][lane] = s * sicnt[op];
    }
    __syncthreads();
#pragma unroll
    for (int r = 0; r < 16; ++r) {
      int cl = r * 4 + g;
      out[((size_t)b * C + c0 + cl) * HW + pix0 + lane] = tr[lane][cl];
    }
    __syncthreads();
  }
}

extern "C" void kernel_launch(void* const* d_in, const int* in_sizes, int n_in,
                              void* d_out, int out_size, void* d_ws, size_t ws_size,
                              hipStream_t stream) {
  (void)in_sizes; (void)n_in; (void)out_size;
  const float* img = (const float*)d_in[0];
  const float* ref = (const float*)d_in[1];
  const float* cl1 = (const float*)d_in[2];   // [4,64,192,192]
  const float* cl2 = (const float*)d_in[3];   // [4,128,96,96]
  const float* cl3 = (const float*)d_in[4];   // [4,256,48,48]
  float* out = (float*)d_out;

  float* ws   = (float*)d_ws;
  float* ps_i = ws;
  float* ps_r = ws + 9216;
  float* ikn  = ws + 18432;
  float* iqn  = ws + 27648;
  int*   ridx = (int*)(ws + 36864);
  float* S    = ws + 46080;

  const long long availf = (long long)(ws_size / 4) - 46080;
  const bool bigS   = availf >= 4 * SSTRIDE;
  const bool lv1all = availf >= 9437184LL;

  k_pixsq<<<576, 256, 0, stream>>>(img, ref, ps_i, ps_r);
  k_norm<<<36, 256, 0, stream>>>(ps_r, ps_i, ikn, iqn);

  if (bigS) {
    k_gemm<<<dim3(18, 18, 4), 256, 0, stream>>>(img, ref, S, 0, SSTRIDE);
    k_argmax2<<<dim3(24, 24, 4), 256, 0, stream>>>(S, ikn, iqn, ridx, out, 0, SSTRIDE);
  } else {
    for (int b = 0; b < 4; ++b) {
      k_gemm<<<dim3(18, 18, 1), 256, 0, stream>>>(img, ref, S, b, 0LL);
      k_argmax2<<<dim3(24, 24, 1), 256, 0, stream>>>(S, ikn, iqn, ridx, out, b, 0LL);
    }
  }

  float* t = S;  // fold scratch reuses S region (argmax complete)

  // lv3: all-batch (t = 4*2304*256 = 2359296 floats, fits known-min region)
  k_tr<<<dim3(36, 4, 4), 256, 0, stream>>>(cl3, t, 256, 2304, 0);
  k_foldgather<<<dim3(36, 4), 256, 0, stream>>>(t, ridx, out + 9216, 256, 48, 1, 0);
  // lv2: all-batch (4718592 floats, fits)
  k_tr<<<dim3(144, 2, 4), 256, 0, stream>>>(cl2, t, 128, 9216, 0);
  k_foldgather<<<dim3(144, 4), 256, 0, stream>>>(t, ridx, out + 2368512, 128, 96, 2, 0);
  // lv1: all-batch if ws allows (9437184 floats), else per-batch (2359296)
  if (lv1all) {
    k_tr<<<dim3(576, 1, 4), 256, 0, stream>>>(cl1, t, 64, 36864, 0);
    k_foldgather<<<dim3(576, 4), 256, 0, stream>>>(t, ridx, out + 7087104, 64, 192, 4, 0);
  } else {
    for (int b = 0; b < 4; ++b) {
      k_tr<<<dim3(576, 1, 1), 256, 0, stream>>>(cl1, t, 64, 36864, b);
      k_foldgather<<<dim3(576, 1), 256, 0, stream>>>(t, ridx, out + 7087104, 64, 192, 4, b);
    }
  }
}

// Round 3
// 800.153 us; speedup vs baseline: 1.0136x; 1.0090x over previous
//
#include <hip/hip_runtime.h>

// SearchTransfer: patch cosine-sim argmax + multi-level gather/fold.
// rel = 9-tap diagonal-shift sum of pixel Gram S (K=256); transfer == gather.
// This round: zero-padded S (no masks in argmax), split-bf16 MFMA GEMM
// (S = Ahi*Bhi + Ahi*Blo + Alo*Bhi, virtual K=768), top-2 + exact f32 rescore.

#define HW3 2304
#define PLANE 589824        // 256*2304
#define MP 2560             // padded+rounded matrix dim (50x50=2500 -> 2560)
#define KP 512              // bf16 plane rows: hi[256] | lo[256]

typedef __bf16 v8bf __attribute__((ext_vector_type(8)));
typedef float v16f __attribute__((ext_vector_type(16)));

// ws float offsets
#define O_PSI  0
#define O_PSR  9216
#define O_IKN  18432
#define O_IQN  27648
#define O_RIDX 36864        // int[9216]
#define O_IKNP 46080        // float[4*2560], NaN at pads
#define O_CAND 56320        // int[4*2304*2]
#define O_IMGT 74752        // float[4*2304*256]
#define O_REFT 2434048
#define O_APL  4793344      // __bf16[4*2560*512] (= 2621440 floats)
#define O_BPL  7414784
#define O_S    10036224     // float[nb*2560*2560]

// ---- per-pixel sum of squares ----
__global__ __launch_bounds__(256) void k_pixsq(const float* __restrict__ img,
                                               const float* __restrict__ ref,
                                               float* __restrict__ psi,
                                               float* __restrict__ psr) {
  __shared__ float ri[16][17], rr[16][17];
  int t = threadIdx.x;
  int pl = t & 15, cg = t >> 4;
  int pix = blockIdx.x * 16 + pl;
  int b = pix / HW3, p = pix - b * HW3;
  const float* ib = img + (size_t)b * PLANE + p;
  const float* rb = ref + (size_t)b * PLANE + p;
  float si = 0.f, sr = 0.f;
#pragma unroll
  for (int c = 0; c < 16; ++c) {
    float x = ib[(cg * 16 + c) * HW3]; si = fmaf(x, x, si);
    float y = rb[(cg * 16 + c) * HW3]; sr = fmaf(y, y, sr);
  }
  ri[pl][cg] = si; rr[pl][cg] = sr;
  __syncthreads();
  if (t < 16) {
    float a = 0.f, s2 = 0.f;
#pragma unroll
    for (int g = 0; g < 16; ++g) { a += ri[t][g]; s2 += rr[t][g]; }
    int pix2 = blockIdx.x * 16 + t;
    psi[pix2] = a; psr[pix2] = s2;
  }
}

// ---- reciprocal patch norms (valid-indexed, for rescore/output) ----
__global__ __launch_bounds__(256) void k_norm(const float* __restrict__ psr,
                                              const float* __restrict__ psi,
                                              float* __restrict__ ikn,
                                              float* __restrict__ iqn) {
  int pix = blockIdx.x * 256 + threadIdx.x;
  int b = pix / HW3, p = pix - b * HW3;
  int py = p / 48, px = p - py * 48;
  float sr = 0.f, si = 0.f;
#pragma unroll
  for (int dy = -1; dy <= 1; ++dy)
#pragma unroll
    for (int dx = -1; dx <= 1; ++dx) {
      if (py + dy < 0 || py + dy >= 48 || px + dx < 0 || px + dx >= 48) continue;
      int n = pix + dy * 48 + dx;
      sr += psr[n]; si += psi[n];
    }
  ikn[pix] = 1.0f / fmaxf(sqrtf(sr), 1e-12f);
  iqn[pix] = 1.0f / fmaxf(sqrtf(si), 1e-12f);
}

// ---- padded reciprocal key norms: NaN at pad positions (never win argmax) ----
__global__ __launch_bounds__(256) void k_normp(const float* __restrict__ psr,
                                               float* __restrict__ iknp) {
  int idx = blockIdx.x * 256 + threadIdx.x;   // [0, 4*2560)
  int b = idx / MP, pp = idx - b * MP;
  int py = pp / 50, px = pp - py * 50;
  float r = __uint_as_float(0x7fc00000u);     // NaN
  if (pp < 2500 && py != 0 && py != 49 && px != 0 && px != 49) {
    int y = py - 1, x = px - 1;
    float s = 0.f;
    for (int dy = -1; dy <= 1; ++dy)
      for (int dx = -1; dx <= 1; ++dx) {
        int yy = y + dy, xx = x + dx;
        if (yy >= 0 && yy < 48 && xx >= 0 && xx < 48)
          s += psr[b * HW3 + yy * 48 + xx];
      }
    r = 1.0f / fmaxf(sqrtf(s), 1e-12f);
  }
  iknp[idx] = r;
}

// ---- transpose+pad+bf16-split: [C][2304] f32 -> [2560 padded pix][hi256|lo256] bf16 ----
__global__ __launch_bounds__(256) void k_padsplit(const float* __restrict__ src,
                                                  __bf16* __restrict__ dst) {
  __shared__ float sm[64][65];
  const int pix0 = blockIdx.x * 64, c0 = blockIdx.y * 64, b = blockIdx.z;
  const int lane = threadIdx.x & 63, q4 = threadIdx.x >> 6;
  const float* s = src + (size_t)b * PLANE;
#pragma unroll
  for (int r = 0; r < 16; ++r) {
    int cl = r * 4 + q4;
    sm[cl][lane] = s[(size_t)(c0 + cl) * HW3 + pix0 + lane];
  }
  __syncthreads();
  __bf16* d = dst + (size_t)b * MP * KP;
#pragma unroll
  for (int r = 0; r < 16; ++r) {
    int pl = r * 4 + q4;
    int p = pix0 + pl;
    int py = p / 48, px = p - py * 48;
    int pp = (py + 1) * 50 + px + 1;
    float v = sm[lane][pl];
    __bf16 hi = (__bf16)v;
    __bf16 lo = (__bf16)(v - (float)hi);
    d[(size_t)pp * KP + c0 + lane] = hi;
    d[(size_t)pp * KP + 256 + c0 + lane] = lo;
  }
}

// ---- plain tiled transpose [C][HW] -> [HW][C] (f32, for rescore + folds) ----
__global__ __launch_bounds__(256) void k_tr(const float* __restrict__ src,
                                            float* __restrict__ dst,
                                            int C, int HW, int b0) {
  __shared__ float sm[64][65];
  int pix0 = blockIdx.x * 64, c0 = blockIdx.y * 64;
  const float* s = src + (size_t)(b0 + blockIdx.z) * C * HW;
  float* d = dst + (size_t)blockIdx.z * HW * C;
  int lane = threadIdx.x & 63, q4 = threadIdx.x >> 6;
#pragma unroll
  for (int r = 0; r < 16; ++r) {
    int cl = r * 4 + q4;
    sm[cl][lane] = s[(size_t)(c0 + cl) * HW + pix0 + lane];
  }
  __syncthreads();
#pragma unroll
  for (int r = 0; r < 16; ++r) {
    int pl = r * 4 + q4;
    d[(size_t)(pix0 + pl) * C + c0 + lane] = sm[lane][pl];
  }
}

// ---- split-bf16 MFMA GEMM: S[q][p] = sum_k A[q][k]*B[p][k], virtual K=768 ----
// 128x128 tile, 4 waves (64x64 each, 2x2 frags of 32x32x16), pad-72 LDS rows.
__global__ __launch_bounds__(256) void k_gemm_mfma(const __bf16* __restrict__ Apl,
                                                   const __bf16* __restrict__ Bpl,
                                                   float* __restrict__ S, int b0) {
  __shared__ __bf16 As[128][72];
  __shared__ __bf16 Bs[128][72];
  const int b = b0 + blockIdx.z;
  const __bf16* Ab = Apl + (size_t)b * MP * KP;
  const __bf16* Bb = Bpl + (size_t)b * MP * KP;
  float* Sb = S + (size_t)blockIdx.z * (2560LL * 2560LL);
  const int t = threadIdx.x;
  const int q0 = blockIdx.y * 128, p0 = blockIdx.x * 128;
  const int lane = t & 63, w = t >> 6, wr = w >> 1, wc = w & 1;
  const int sr = t >> 1, ss = (t & 1) * 32;
  const int l31 = lane & 31, kb = (lane >> 5) * 8;

  v16f acc[2][2];
#pragma unroll
  for (int i = 0; i < 2; ++i)
#pragma unroll
    for (int j = 0; j < 2; ++j)
#pragma unroll
      for (int e = 0; e < 16; ++e) acc[i][j][e] = 0.f;

  for (int kv = 0; kv < 768; kv += 64) {
    const int ak = kv < 256 ? kv : kv - 256;   // Ahi, Ahi, Alo
    const int bk = kv < 512 ? kv : kv - 512;   // Bhi, Blo, Bhi
    const __bf16* ga = Ab + (size_t)(q0 + sr) * KP + ak + ss;
    const __bf16* gb = Bb + (size_t)(p0 + sr) * KP + bk + ss;
    float4 a0 = *(const float4*)(ga);
    float4 a1 = *(const float4*)(ga + 8);
    float4 a2 = *(const float4*)(ga + 16);
    float4 a3 = *(const float4*)(ga + 24);
    float4 b0v = *(const float4*)(gb);
    float4 b1v = *(const float4*)(gb + 8);
    float4 b2v = *(const float4*)(gb + 16);
    float4 b3v = *(const float4*)(gb + 24);
    __syncthreads();
    *(float4*)(&As[sr][ss])      = a0;
    *(float4*)(&As[sr][ss + 8])  = a1;
    *(float4*)(&As[sr][ss + 16]) = a2;
    *(float4*)(&As[sr][ss + 24]) = a3;
    *(float4*)(&Bs[sr][ss])      = b0v;
    *(float4*)(&Bs[sr][ss + 8])  = b1v;
    *(float4*)(&Bs[sr][ss + 16]) = b2v;
    *(float4*)(&Bs[sr][ss + 24]) = b3v;
    __syncthreads();
#pragma unroll
    for (int kk = 0; kk < 4; ++kk) {
      const int ko = kk * 16 + kb;
      v8bf af0 = *(const v8bf*)(&As[wr * 64 + l31][ko]);
      v8bf af1 = *(const v8bf*)(&As[wr * 64 + 32 + l31][ko]);
      v8bf bg0 = *(const v8bf*)(&Bs[wc * 64 + l31][ko]);
      v8bf bg1 = *(const v8bf*)(&Bs[wc * 64 + 32 + l31][ko]);
      acc[0][0] = __builtin_amdgcn_mfma_f32_32x32x16_bf16(af0, bg0, acc[0][0], 0, 0, 0);
      acc[0][1] = __builtin_amdgcn_mfma_f32_32x32x16_bf16(af0, bg1, acc[0][1], 0, 0, 0);
      acc[1][0] = __builtin_amdgcn_mfma_f32_32x32x16_bf16(af1, bg0, acc[1][0], 0, 0, 0);
      acc[1][1] = __builtin_amdgcn_mfma_f32_32x32x16_bf16(af1, bg1, acc[1][1], 0, 0, 0);
    }
  }
#pragma unroll
  for (int mf = 0; mf < 2; ++mf)
#pragma unroll
    for (int nf = 0; nf < 2; ++nf) {
      const int col = p0 + wc * 64 + nf * 32 + l31;
#pragma unroll
      for (int r = 0; r < 16; ++r) {
        const int row = q0 + wr * 64 + mf * 32 + (r & 3) + 8 * (r >> 2) + 4 * (lane >> 5);
        Sb[(size_t)row * MP + col] = acc[mf][nf][r];
      }
    }
}

__device__ __forceinline__ void top2merge(float& b1, int& i1, float& b2, int& i2,
                                          float o1, int oj1, float o2, int oj2) {
  if (o1 > b1 || (o1 == b1 && oj1 < i1)) {
    float t1 = b1; int tj = i1;
    b1 = o1; i1 = oj1;
    if (o2 > t1 || (o2 == t1 && oj2 < tj)) { b2 = o2; i2 = oj2; }
    else { b2 = t1; i2 = tj; }
  } else if (o1 > b2 || (o1 == b2 && oj1 < i2)) {
    b2 = o1; i2 = oj1;
  }
}

// ---- argmax over padded keys: 8 queries (one qy, 8 qx) per block, top-2 ----
__global__ __launch_bounds__(256) void k_argmax_pad(const float* __restrict__ S,
                                                    const float* __restrict__ iknp,
                                                    int* __restrict__ cand, int b0) {
  __shared__ float L[30 * 258];     // 3 row-groups x 10 rows x 258 cols
  __shared__ float smv[8][4][2];
  __shared__ int   smi[8][4][2];
  const int b = b0 + blockIdx.z;
  const float* Sb = S + (size_t)blockIdx.z * (2560LL * 2560LL);
  const float* ik = iknp + b * MP;
  const int qy = blockIdx.y, qx0 = blockIdx.x * 8;
  const int t = threadIdx.x, lane = t & 63, wv = t >> 6;
  const int gb[3] = { qy * 50 + qx0, (qy + 1) * 50 + qx0, (qy + 2) * 50 + qx0 };

  float b1[8], b2[8]; int i1[8], i2[8];
#pragma unroll
  for (int a = 0; a < 8; ++a) { b1[a] = -3e38f; b2[a] = -3e38f; i1[a] = 51; i2[a] = 51; }

  for (int pc = 0; pc < MP; pc += 256) {
    for (int row = wv; row < 30; row += 4) {
      int g = (row >= 20) ? 2 : (row >= 10 ? 1 : 0);
      int rr = row - g * 10;
      int gbase = (g == 0) ? gb[0] : (g == 1 ? gb[1] : gb[2]);
      int cb = pc + 50 * (g - 1) - 1;
      const float* src = Sb + (size_t)(gbase + rr) * MP;
      float* dstL = L + row * 258;
      for (int c = lane; c < 258; c += 64) {
        int cg = cb + c;
        float v = 0.f;
        if (cg >= 0 && cg < MP) v = src[cg];
        dstL[c] = v;
      }
    }
    __syncthreads();
    const float ikv = ik[pc + t];
    const int p = pc + t;
#pragma unroll
    for (int a = 0; a < 8; ++a) {
      float s = 0.f;
#pragma unroll
      for (int g = 0; g < 3; ++g)
#pragma unroll
        for (int dx = -1; dx <= 1; ++dx)
          s += L[(g * 10 + a + dx + 1) * 258 + (t + dx + 1)];
      float v = s * ikv;   // NaN at pads -> never wins
      if (v > b1[a]) { b2[a] = b1[a]; i2[a] = i1[a]; b1[a] = v; i1[a] = p; }
      else if (v > b2[a]) { b2[a] = v; i2[a] = p; }
    }
    __syncthreads();
  }

#pragma unroll
  for (int a = 0; a < 8; ++a) {
    float x1 = b1[a], x2 = b2[a]; int j1 = i1[a], j2 = i2[a];
#pragma unroll
    for (int off = 32; off; off >>= 1) {
      float o1 = __shfl_down(x1, off), o2 = __shfl_down(x2, off);
      int oj1 = __shfl_down(j1, off), oj2 = __shfl_down(j2, off);
      top2merge(x1, j1, x2, j2, o1, oj1, o2, oj2);
    }
    if (lane == 0) { smv[a][wv][0] = x1; smv[a][wv][1] = x2; smi[a][wv][0] = j1; smi[a][wv][1] = j2; }
  }
  __syncthreads();
  if (t < 8) {
    float x1 = smv[t][0][0], x2 = smv[t][0][1]; int j1 = smi[t][0][0], j2 = smi[t][0][1];
#pragma unroll
    for (int w2 = 1; w2 < 4; ++w2)
      top2merge(x1, j1, x2, j2, smv[t][w2][0], smi[t][w2][0], smv[t][w2][1], smi[t][w2][1]);
    int q = qy * 48 + qx0 + t;
    cand[((size_t)b * HW3 + q) * 2]     = j1;
    cand[((size_t)b * HW3 + q) * 2 + 1] = j2;
  }
}

// ---- exact f32 rescore of the two candidates; final idx + S output ----
__global__ __launch_bounds__(256) void k_rescore(const float* __restrict__ imgT,
                                                 const float* __restrict__ refT,
                                                 const float* __restrict__ ikn,
                                                 const float* __restrict__ iqn,
                                                 const int* __restrict__ cand,
                                                 int* __restrict__ ridx,
                                                 float* __restrict__ outS) {
  const int t = threadIdx.x, lane = t & 63, sub = t >> 6;
  const int qg = blockIdx.x * 4 + sub;
  const int b = qg / HW3, q = qg - b * HW3;
  const int qy = q / 48, qx = q - qy * 48;
  const float* iT = imgT + (size_t)b * HW3 * 256;
  const float* rT = refT + (size_t)b * HW3 * 256;
  const int c0 = cand[qg * 2], c1 = cand[qg * 2 + 1];
  const int p0y = c0 / 50 - 1, p0x = c0 % 50 - 1;
  const int p1y = c1 / 50 - 1, p1x = c1 % 50 - 1;
  float s0 = 0.f, s1 = 0.f;
  for (int dy = -1; dy <= 1; ++dy) {
    int yq = qy + dy; if (yq < 0 || yq >= 48) continue;
    for (int dx = -1; dx <= 1; ++dx) {
      int xq = qx + dx; if (xq < 0 || xq >= 48) continue;
      const float* qrow = iT + (size_t)(yq * 48 + xq) * 256;
      int y0 = p0y + dy, x0 = p0x + dx;
      int y1 = p1y + dy, x1 = p1x + dx;
      bool v0 = (y0 >= 0 && y0 < 48 && x0 >= 0 && x0 < 48);
      bool v1 = (y1 >= 0 && y1 < 48 && x1 >= 0 && x1 < 48);
      const float* r0 = rT + (size_t)((v0 ? y0 * 48 + x0 : 0)) * 256;
      const float* r1 = rT + (size_t)((v1 ? y1 * 48 + x1 : 0)) * 256;
#pragma unroll
      for (int j = 0; j < 4; ++j) {
        float qv = qrow[lane + j * 64];
        if (v0) s0 = fmaf(qv, r0[lane + j * 64], s0);
        if (v1) s1 = fmaf(qv, r1[lane + j * 64], s1);
      }
    }
  }
#pragma unroll
  for (int off = 32; off; off >>= 1) {
    s0 += __shfl_down(s0, off);
    s1 += __shfl_down(s1, off);
  }
  if (lane == 0) {
    int m0 = p0y * 48 + p0x, m1 = p1y * 48 + p1x;
    float v0 = s0 * ikn[b * HW3 + m0], v1 = s1 * ikn[b * HW3 + m1];
    int win; float vw;
    if (v1 > v0 || (v1 == v0 && m1 < m0)) { win = m1; vw = v1; }
    else { win = m0; vw = v0; }
    ridx[b * HW3 + q] = win;
    outS[qg] = vw * iqn[b * HW3 + q];
  }
}

// ---- gather+fold in channel-last, coalesced, LDS transpose on write ----
__global__ __launch_bounds__(256) void k_foldgather(const float* __restrict__ t,
                                                    const int* __restrict__ ridx,
                                                    float* __restrict__ out,
                                                    int C, int H, int sc, int b0) {
  __shared__ int   soff[64][9];
  __shared__ float sicnt[64];
  __shared__ float tr[64][65];
  const int HW = H * H;
  const int b = b0 + blockIdx.y;
  const float* tb = t + (size_t)blockIdx.y * HW * C;
  const int* rb = ridx + b * HW3;
  const int pix0 = blockIdx.x * 64;

  for (int e = threadIdx.x; e < 576; e += 256) {
    int op = e / 9, tap = e - op * 9;
    int pix = pix0 + op;
    int h = pix / H, w = pix - h * H;
    int hi = h / sc, hr = h - hi * sc;
    int wi = w / sc, wr = w - wi * sc;
    int ii = tap / 3, jj = tap - ii * 3;
    int oy = hi + 1 - ii, ox = wi + 1 - jj;
    int off = -1;
    if (oy >= 0 && oy < 48 && ox >= 0 && ox < 48) {
      int m = rb[oy * 48 + ox];
      int my = m / 48, mx = m - my * 48;
      int y = sc * (my - 1 + ii) + hr;
      int x = sc * (mx - 1 + jj) + wr;
      if (y >= 0 && y < H && x >= 0 && x < H) off = y * H + x;
    }
    soff[op][tap] = off;
    if (tap == 0) {
      int cnt = 0;
#pragma unroll
      for (int i2 = 0; i2 < 3; ++i2)
#pragma unroll
        for (int j2 = 0; j2 < 3; ++j2) {
          int oy2 = hi + 1 - i2, ox2 = wi + 1 - j2;
          if (oy2 >= 0 && oy2 < 48 && ox2 >= 0 && ox2 < 48) ++cnt;
        }
      sicnt[op] = 1.0f / (float)cnt;
    }
  }
  __syncthreads();

  const int g = threadIdx.x >> 6, lane = threadIdx.x & 63;
  for (int c0 = 0; c0 < C; c0 += 64) {
#pragma unroll
    for (int o = 0; o < 16; ++o) {
      int op = g * 16 + o;
      float s = 0.f;
#pragma unroll
      for (int tp = 0; tp < 9; ++tp) {
        int off = soff[op][tp];
        if (off >= 0) s += tb[(size_t)off * C + c0 + lane];
      }
      tr[op][lane] = s * sicnt[op];
    }
    __syncthreads();
#pragma unroll
    for (int r = 0; r < 16; ++r) {
      int cl = r * 4 + g;
      out[((size_t)b * C + c0 + cl) * HW + pix0 + lane] = tr[lane][cl];
    }
    __syncthreads();
  }
}

extern "C" void kernel_launch(void* const* d_in, const int* in_sizes, int n_in,
                              void* d_out, int out_size, void* d_ws, size_t ws_size,
                              hipStream_t stream) {
  (void)in_sizes; (void)n_in; (void)out_size;
  const float* img = (const float*)d_in[0];
  const float* ref = (const float*)d_in[1];
  const float* cl1 = (const float*)d_in[2];   // [4,64,192,192]
  const float* cl2 = (const float*)d_in[3];   // [4,128,96,96]
  const float* cl3 = (const float*)d_in[4];   // [4,256,48,48]
  float* out = (float*)d_out;

  float* ws   = (float*)d_ws;
  float* ps_i = ws + O_PSI;
  float* ps_r = ws + O_PSR;
  float* ikn  = ws + O_IKN;
  float* iqn  = ws + O_IQN;
  int*   ridx = (int*)(ws + O_RIDX);
  float* iknp = ws + O_IKNP;
  int*   cand = (int*)(ws + O_CAND);
  float* imgT = ws + O_IMGT;
  float* refT = ws + O_REFT;
  __bf16* Apl = (__bf16*)(ws + O_APL);
  __bf16* Bpl = (__bf16*)(ws + O_BPL);
  float* Sm   = ws + O_S;

  // zero bf16 planes (pad pixels must be 0)
  hipMemsetAsync(ws + O_APL, 0, (size_t)(O_S - O_APL) * 4, stream);

  k_pixsq<<<576, 256, 0, stream>>>(img, ref, ps_i, ps_r);
  k_norm<<<36, 256, 0, stream>>>(ps_r, ps_i, ikn, iqn);
  k_normp<<<40, 256, 0, stream>>>(ps_r, iknp);
  k_padsplit<<<dim3(36, 4, 4), 256, 0, stream>>>(img, Apl);
  k_padsplit<<<dim3(36, 4, 4), 256, 0, stream>>>(ref, Bpl);
  k_tr<<<dim3(36, 4, 4), 256, 0, stream>>>(img, imgT, 256, HW3, 0);
  k_tr<<<dim3(36, 4, 4), 256, 0, stream>>>(ref, refT, 256, HW3, 0);

  const long long SPF = 2560LL * 2560LL;
  const long long availf = (long long)(ws_size / 4) - O_S;
  const int nb = (availf >= 4 * SPF) ? 4 : ((availf >= 2 * SPF) ? 2 : 1);
  for (int g = 0; g < 4; g += nb) {
    k_gemm_mfma<<<dim3(20, 20, nb), 256, 0, stream>>>(Apl, Bpl, Sm, g);
    k_argmax_pad<<<dim3(6, 48, nb), 256, 0, stream>>>(Sm, iknp, cand, g);
  }
  k_rescore<<<2304, 256, 0, stream>>>(imgT, refT, ikn, iqn, cand, ridx, out);

  // folds (scratch reuses imgT.. region; all search inputs dead by now)
  float* t = ws + O_IMGT;
  k_tr<<<dim3(36, 4, 4), 256, 0, stream>>>(cl3, t, 256, 2304, 0);
  k_foldgather<<<dim3(36, 4), 256, 0, stream>>>(t, ridx, out + 9216, 256, 48, 1, 0);
  k_tr<<<dim3(144, 2, 4), 256, 0, stream>>>(cl2, t, 128, 9216, 0);
  k_foldgather<<<dim3(144, 4), 256, 0, stream>>>(t, ridx, out + 2368512, 128, 96, 2, 0);
  k_tr<<<dim3(576, 1, 4), 256, 0, stream>>>(cl1, t, 64, 36864, 0);
  k_foldgather<<<dim3(576, 4), 256, 0, stream>>>(t, ridx, out + 7087104, 64, 192, 4, 0);
}